// Round 12
// baseline (179.660 us; speedup 1.0000x reference)
//
#include <hip/hip_runtime.h>
#include <hip/hip_bf16.h>

// MoE top-1, single fused persistent kernel (256 blocks x 256 thr).
// N=8192, D=256, H=64, E=32, fp32 (no fp32 MFMA on CDNA4 -> VALU).
// Phase 1: router (block g -> tokens [32g,32g+32)), writes eidx + hist row.
// Device-scope flag barrier (poison-proof MAGIC, co-residency guaranteed:
//   73.7 KB LDS -> 2 blocks/CU capacity = 512 >= 256 grid).
// Phase 2: counts from hist; per tile (<=3 passes): rank-scan of eidx
//   collects the tile's tokens; then round-11-verbatim ffn core.
//
// ws ints: hist[256][32] @0 | eidx[8192] @8192 | arrive[256] @16384

constexpr int D = 256;
constexpr int H = 64;
constexpr int E = 32;
constexpr int T_TILE = 16;
constexpr int NBLK = 256;
constexpr int HIST = 0;
constexpr int EIDX = 8192;
constexpr int ARR  = 16384;
constexpr int MAGIC = 0x51C0FFEE;   // != 0xAAAAAAAA poison

__device__ __forceinline__ float quad_reduce(float v) {
    // sum across the 4 lanes of each quad via DPP quad_perm (VALU-only)
    int i1 = __builtin_bit_cast(int, v);
    v += __builtin_bit_cast(float,
        __builtin_amdgcn_mov_dpp(i1, 0xB1, 0xF, 0xF, true));   // [1,0,3,2]
    int i2 = __builtin_bit_cast(int, v);
    v += __builtin_bit_cast(float,
        __builtin_amdgcn_mov_dpp(i2, 0x4E, 0xF, 0xF, true));   // [2,3,0,1]
    return v;
}

union SU {
    struct {                            // router phase (~71.3 KB)
        float4 xs[32][65];
        float4 rwt[64][33];             // [k4][e], padded
        float  logitS[32][E + 1];
    } r;
    struct {                            // ffn phase (20.5 KB)
        float part[4][T_TILE][H];
        float hsl[T_TILE][H];
    } f;
};

__global__ __launch_bounds__(256) void fused_moe(
    const float* __restrict__ x,  const float* __restrict__ rw,
    const float* __restrict__ rb, const float* __restrict__ W1,
    const float* __restrict__ b1, const float* __restrict__ W2,
    const float* __restrict__ b2, int* __restrict__ wsp,
    float* __restrict__ out)
{
    __shared__ SU su;
    __shared__ int lcnt[E];
    __shared__ int cfull[8][E];
    __shared__ int cs[E];
    __shared__ int scan_s[256];
    __shared__ int rowsl[T_TILE];
    __shared__ int ntile_s;

    const int t = threadIdx.x;
    const int g = blockIdx.x;
    const int n0 = g * 32;

    // ================= phase 1: router (round-11 verbatim math) ==========
    {
        if (t < E) lcnt[t] = 0;
        const float4* x4 = (const float4*)x;
        const float4* rw4 = (const float4*)rw;
        for (int i = t; i < 32 * 64; i += 256) {
            int r = i >> 6, qq = i & 63;
            su.r.xs[r][qq] = x4[(size_t)(n0 + r) * 64 + qq];
            su.r.rwt[qq][r] = rw4[i];
        }
        __syncthreads();

        {
            const int e = t & 31, gg = t >> 5;
            float s[4];
#pragma unroll
            for (int j = 0; j < 4; ++j) s[j] = rb[e];
#pragma unroll
            for (int p = 0; p < 8; ++p) {
                float sp[4] = {0.f, 0.f, 0.f, 0.f};
#pragma unroll
                for (int k4 = 0; k4 < 8; ++k4) {
                    float4 wv = su.r.rwt[p * 8 + k4][e];
#pragma unroll
                    for (int j = 0; j < 4; ++j) {
                        float4 xv = su.r.xs[gg * 4 + j][p * 8 + k4];
                        sp[j] = fmaf(xv.x, wv.x, sp[j]);
                        sp[j] = fmaf(xv.y, wv.y, sp[j]);
                        sp[j] = fmaf(xv.z, wv.z, sp[j]);
                        sp[j] = fmaf(xv.w, wv.w, sp[j]);
                    }
                }
#pragma unroll
                for (int j = 0; j < 4; ++j) s[j] += sp[j];
            }
#pragma unroll
            for (int j = 0; j < 4; ++j) su.r.logitS[gg * 4 + j][e] = s[j];
        }
        __syncthreads();

        if (t < 32) {
            float best = su.r.logitS[t][0];
            int bi = 0;
#pragma unroll
            for (int i = 1; i < E; ++i) {
                float v = su.r.logitS[t][i];
                if (v > best) { best = v; bi = i; }  // strict >: first occur.
            }
            wsp[EIDX + n0 + t] = bi;
            atomicAdd(&lcnt[bi], 1);                 // LDS atomic only
        }
        __syncthreads();
        if (t < E) wsp[HIST + g * E + t] = lcnt[t];
    }

    // ================= device-scope flag barrier ========================
    __syncthreads();
    __threadfence();                    // all threads: flush own writes
    if (t == 0)
        __hip_atomic_store(&wsp[ARR + g], MAGIC,
                           __ATOMIC_RELEASE, __HIP_MEMORY_SCOPE_AGENT);
    // every thread polls one block's flag (t in [0,256) == NBLK)
    while (__hip_atomic_load(&wsp[ARR + t],
                             __ATOMIC_ACQUIRE, __HIP_MEMORY_SCOPE_AGENT)
           != MAGIC)
        __builtin_amdgcn_s_sleep(2);
    __syncthreads();

    // ================= counts + tile count ==============================
    {
        const int c = t >> 5, e2 = t & 31;
        int full = 0;
        for (int i = 0; i < 32; ++i)
            full += wsp[HIST + (c * 32 + i) * E + e2];   // coalesced, L2-hot
        cfull[c][e2] = full;
    }
    __syncthreads();
    if (t < E) {
        int tot = 0;
#pragma unroll
        for (int c2 = 0; c2 < 8; ++c2) tot += cfull[c2][t];
        cs[t] = tot;
    }
    __syncthreads();
    if (t == 0) {
        int nt = 0;
        for (int e2 = 0; e2 < E; ++e2) nt += (cs[e2] + 15) >> 4;
        ntile_s = nt;
    }
    __syncthreads();
    const int numTiles = ntile_s;       // in [512, 543]

    const int lane = t & 63;
    const int w = t >> 6;
    const int s = lane & 3;
    const int q = lane >> 2;

    // ================= phase 2: ffn tiles ===============================
    for (int pass = 0; pass < 3; ++pass) {
        const int tile = g + pass * NBLK;
        if (tile >= numTiles) break;    // uniform across block
        __syncthreads();                // protect LDS reuse across passes

        // self-locate (every thread; uniform)
        int e = -1, slot = 0;
        {
            int b = tile;
#pragma unroll 1
            for (int e2 = 0; e2 < E; ++e2) {
                const int nt = (cs[e2] + 15) >> 4;
                if (e < 0) {
                    if (b < nt) { e = e2; slot = b; }
                    else b -= nt;
                }
            }
        }
        const int lo = slot * 16;
        const int cnt = min(T_TILE, cs[e] - lo);

        // token collection: rank-scan of eidx (thread t owns [32t,32t+32))
        int mycount = 0;
        {
            const int* ep = wsp + EIDX + 32 * t;
#pragma unroll
            for (int i = 0; i < 32; ++i) mycount += (ep[i] == e);
        }
        scan_s[t] = mycount;
        __syncthreads();
        for (int d2 = 1; d2 < 256; d2 <<= 1) {      // Hillis-Steele
            int v = scan_s[t];
            int u = (t >= d2) ? scan_s[t - d2] : 0;
            __syncthreads();
            scan_s[t] = v + u;
            __syncthreads();
        }
        {
            int r = scan_s[t] - mycount;            // exclusive base
            const int* ep = wsp + EIDX + 32 * t;
#pragma unroll
            for (int i = 0; i < 32; ++i) {
                if (ep[i] == e) {
                    if (r >= lo && r < lo + T_TILE) rowsl[r - lo] = 32 * t + i;
                    ++r;
                }
            }
        }
        __syncthreads();

        // -------- ffn core (round-11 verbatim) --------
        const float* w1e = W1 + (size_t)e * (D * H);
        float4 w1v[16];
        {
            const float* base = w1e + (size_t)((w * 4 + s) * 16) * H + 4 * q;
#pragma unroll
            for (int k = 0; k < 16; ++k)
                w1v[k] = *(const float4*)(base + k * H);
        }

#define LOADX(buf, row) {                                                  \
        const float* xb_ = x + (size_t)(row) * D + (w * 4 + s) * 16;       \
        buf[0] = *(const float4*)(xb_ + 0);                                \
        buf[1] = *(const float4*)(xb_ + 4);                                \
        buf[2] = *(const float4*)(xb_ + 8);                                \
        buf[3] = *(const float4*)(xb_ + 12); }

#define BODY1(tok, xb) {                                                   \
        float sp0 = 0.f, sp1 = 0.f, sp2 = 0.f, sp3 = 0.f;                  \
        _Pragma("unroll")                                                  \
        for (int k4 = 0; k4 < 4; ++k4) {                                   \
            float4 xv = xb[k4];                                            \
            _Pragma("unroll")                                              \
            for (int m = 0; m < 4; ++m) {                                  \
                const int k = k4 * 4 + m;                                  \
                const float xs_ = (m == 0) ? xv.x : (m == 1) ? xv.y        \
                                 : (m == 2) ? xv.z : xv.w;                 \
                sp0 = fmaf(xs_, w1v[k].x, sp0);                            \
                sp1 = fmaf(xs_, w1v[k].y, sp1);                            \
                sp2 = fmaf(xs_, w1v[k].z, sp2);                            \
                sp3 = fmaf(xs_, w1v[k].w, sp3);                            \
            }                                                              \
        }                                                                  \
        sp0 = quad_reduce(sp0); sp1 = quad_reduce(sp1);                    \
        sp2 = quad_reduce(sp2); sp3 = quad_reduce(sp3);                    \
        float a_ = (s & 1) ? sp1 : sp0;                                    \
        float c_ = (s & 1) ? sp3 : sp2;                                    \
        su.f.part[w][tok][4 * q + s] = (s & 2) ? c_ : a_; }

        {
            float4 xa[4], xb4[4];
            LOADX(xa, rowsl[0]);
            for (int tok = 0; tok < cnt; tok += 2) {
                if (tok + 1 < cnt) LOADX(xb4, rowsl[tok + 1]);
                BODY1(tok, xa);
                if (tok + 1 < cnt) {
                    if (tok + 2 < cnt) LOADX(xa, rowsl[tok + 2]);
                    BODY1(tok + 1, xb4);
                }
            }
        }

        // W2 staging overlaps the barrier + relu phase
        const float* w2e = W2 + (size_t)e * (H * D);
        float4 w2v[16];
        {
            const float* base = w2e + (size_t)(16 * s) * D + 64 * w + 4 * q;
#pragma unroll
            for (int k = 0; k < 16; ++k)
                w2v[k] = *(const float4*)(base + k * D);
        }
        const float b2v = b2[e * D + 64 * w + 4 * q + s];
        __syncthreads();

        // cross-wave reduce + bias + relu -> hsl
        {
            const int h = t & 63;
            const int tq = t >> 6;
            const float b1v = b1[e * H + h];
#pragma unroll
            for (int r2 = 0; r2 < 4; ++r2) {
                const int tok = tq * 4 + r2;
                if (tok < cnt) {
                    float v = su.f.part[0][tok][h] + su.f.part[1][tok][h]
                            + su.f.part[2][tok][h] + su.f.part[3][tok][h] + b1v;
                    su.f.hsl[tok][h] = fmaxf(v, 0.f);
                }
            }
        }
        __syncthreads();

#define LOADH(buf, tok) {                                                  \
        const float* hb_ = &su.f.hsl[tok][s * 16];                         \
        buf[0] = *(const float4*)(hb_ + 0);                                \
        buf[1] = *(const float4*)(hb_ + 4);                                \
        buf[2] = *(const float4*)(hb_ + 8);                                \
        buf[3] = *(const float4*)(hb_ + 12); }

#define BODY2(tok, hb) {                                                   \
        float sp0 = 0.f, sp1 = 0.f, sp2 = 0.f, sp3 = 0.f;                  \
        _Pragma("unroll")                                                  \
        for (int k4 = 0; k4 < 4; ++k4) {                                   \
            float4 hv = hb[k4];                                            \
            _Pragma("unroll")                                              \
            for (int m = 0; m < 4; ++m) {                                  \
                const int k = k4 * 4 + m;                                  \
                const float hs_ = (m == 0) ? hv.x : (m == 1) ? hv.y        \
                                 : (m == 2) ? hv.z : hv.w;                 \
                sp0 = fmaf(hs_, w2v[k].x, sp0);                            \
                sp1 = fmaf(hs_, w2v[k].y, sp1);                            \
                sp2 = fmaf(hs_, w2v[k].z, sp2);                            \
                sp3 = fmaf(hs_, w2v[k].w, sp3);                            \
            }                                                              \
        }                                                                  \
        sp0 = quad_reduce(sp0); sp1 = quad_reduce(sp1);                    \
        sp2 = quad_reduce(sp2); sp3 = quad_reduce(sp3);                    \
        float a_ = (s & 1) ? sp1 : sp0;                                    \
        float c_ = (s & 1) ? sp3 : sp2;                                    \
        const float val_ = ((s & 2) ? c_ : a_) + b2v;                      \
        const int row_ = rowsl[tok];                                       \
        out[(size_t)row_ * D + 64 * w + 4 * q + s] = fmaxf(val_, 0.f); }

        {
            float4 ha[4], hb4[4];
            LOADH(ha, 0);
            for (int tok = 0; tok < cnt; tok += 2) {
                if (tok + 1 < cnt) LOADH(hb4, tok + 1);
                BODY2(tok, ha);
                if (tok + 1 < cnt) {
                    if (tok + 2 < cnt) LOADH(ha, tok + 2);
                    BODY2(tok + 1, hb4);
                }
            }
        }
#undef LOADX
#undef BODY1
#undef LOADH
#undef BODY2
    }
}

extern "C" void kernel_launch(void* const* d_in, const int* in_sizes, int n_in,
                              void* d_out, int out_size, void* d_ws, size_t ws_size,
                              hipStream_t stream) {
    const float* x  = (const float*)d_in[0];
    const float* rw = (const float*)d_in[1];
    const float* rb = (const float*)d_in[2];
    const float* W1 = (const float*)d_in[3];
    const float* b1 = (const float*)d_in[4];
    const float* W2 = (const float*)d_in[5];
    const float* b2 = (const float*)d_in[6];
    float* out = (float*)d_out;
    int* ws = (int*)d_ws;

    fused_moe<<<NBLK, 256, 0, stream>>>(x, rw, rb, W1, b1, W2, b2, ws, out);
}